// Round 2
// baseline (758.888 us; speedup 1.0000x reference)
//
#include <hip/hip_runtime.h>

#define B_ 8
#define S_ 1024
#define D_ 768
#define H_ 12
#define DH_ 64

typedef __attribute__((ext_vector_type(8))) short short8;
typedef __attribute__((ext_vector_type(4))) short short4v;
typedef __attribute__((ext_vector_type(4))) float float4v;
typedef __attribute__((ext_vector_type(8))) __bf16 bf16x8;

static __device__ __forceinline__ short f2bf(float f) {
  union { float f; unsigned u; } v; v.f = f;
  unsigned r = v.u + 0x7fffu + ((v.u >> 16) & 1u);
  return (short)(r >> 16);
}

static __device__ __forceinline__ float4v mfma16(const short* ap, const short* bp, float4v c) {
  bf16x8 a = *(const bf16x8*)ap;
  bf16x8 b = *(const bf16x8*)bp;
  return __builtin_amdgcn_mfma_f32_16x16x32_bf16(a, b, c, 0, 0, 0);
}

// ---------------- fp32 -> bf16 conversion ----------------
__global__ __launch_bounds__(256) void cvt_bf16(const float* __restrict__ src,
                                                short* __restrict__ dst, int n4) {
  int i = blockIdx.x * 256 + threadIdx.x;
  if (i < n4) {
    float4v v = ((const float4v*)src)[i];
    short4v o;
    o.x = f2bf(v.x); o.y = f2bf(v.y); o.z = f2bf(v.z); o.w = f2bf(v.w);
    ((short4v*)dst)[i] = o;
  }
}

// ---------------- QKV projection GEMM (NT): C[8192][2304] = hs_bf16 @ Wqkv^T ----------------
// 128x128 tile, BK=32, 4 waves (2x2), each wave 64x64 (4x4 frags of 16x16x32)
#define AST 56  // padded LDS row stride in shorts (32 + 24): 112B, 16B-aligned, 2-way-free banks

__global__ __launch_bounds__(256) void gemm_qkv(const short* __restrict__ A,
                                                const short* __restrict__ Bw,
                                                const float* __restrict__ bq,
                                                const float* __restrict__ bk,
                                                const float* __restrict__ bv,
                                                short* __restrict__ Qb,
                                                short* __restrict__ Kb,
                                                short* __restrict__ Vtb) {
  __shared__ short As[128][AST];
  __shared__ short Bs[128][AST];
  int m0 = blockIdx.x * 128, n0 = blockIdx.y * 128;
  int t = threadIdx.x;
  int w = t >> 6, lane = t & 63;
  int wm = (w >> 1) * 64, wn = (w & 1) * 64;
  int lr = lane & 15, lk = (lane >> 4) * 8;
  int sr = t >> 2, sc = (t & 3) * 8;

  float4v acc[4][4] = {};

  for (int k0 = 0; k0 < 768; k0 += 32) {
    *(short8*)&As[sr][sc]      = *(const short8*)&A[(size_t)(m0 + sr) * 768 + k0 + sc];
    *(short8*)&As[sr + 64][sc] = *(const short8*)&A[(size_t)(m0 + sr + 64) * 768 + k0 + sc];
    *(short8*)&Bs[sr][sc]      = *(const short8*)&Bw[(size_t)(n0 + sr) * 768 + k0 + sc];
    *(short8*)&Bs[sr + 64][sc] = *(const short8*)&Bw[(size_t)(n0 + sr + 64) * 768 + k0 + sc];
    __syncthreads();
    short8 a[4], b[4];
#pragma unroll
    for (int i = 0; i < 4; i++) a[i] = *(const short8*)&As[wm + i * 16 + lr][lk];
#pragma unroll
    for (int j = 0; j < 4; j++) b[j] = *(const short8*)&Bs[wn + j * 16 + lr][lk];
#pragma unroll
    for (int i = 0; i < 4; i++)
#pragma unroll
      for (int j = 0; j < 4; j++)
        acc[i][j] = mfma16((const short*)&a[i], (const short*)&b[j], acc[i][j]);
    __syncthreads();
  }

  int proj = n0 / 768;
  int nloc0 = n0 - proj * 768;
  const float* bias = (proj == 0) ? bq : ((proj == 1) ? bk : bv);
#pragma unroll
  for (int j = 0; j < 4; j++) {
    int gn = nloc0 + wn + j * 16 + lr;  // 0..767 within projection
    int hh = gn >> 6, dh = gn & 63;
    float bb = bias[gn];
#pragma unroll
    for (int i = 0; i < 4; i++) {
      int gm0 = m0 + wm + i * 16 + ((lane >> 4) << 2);
#pragma unroll
      for (int jj = 0; jj < 4; jj++) {
        int r = gm0 + jj;
        int bidx = r >> 10, s = r & 1023;
        short val = f2bf(acc[i][j][jj] + bb);
        if (proj == 2)
          Vtb[(((size_t)bidx * 12 + hh) * 64 + dh) * 1024 + s] = val;
        else {
          short* dst = (proj == 0) ? Qb : Kb;
          dst[(((size_t)bidx * 12 + hh) * 1024 + s) * 64 + dh] = val;
        }
      }
    }
  }
}

// ---------------- fused attention: per (b,h,q-tile of 16) ----------------
// scores (16x1024) in regs (4 waves x 256 cols), softmax, probs write, PV (k-split)
__global__ __launch_bounds__(256) void attn_fused(const short* __restrict__ Qb,
                                                  const short* __restrict__ Kb,
                                                  const short* __restrict__ Vtb,
                                                  const int* __restrict__ amask,
                                                  float* __restrict__ probs,
                                                  short* __restrict__ ctxb) {
  __shared__ short P[16][1032];     // P bf16, padded (2064B stride: 16B-aligned, 2-way banks)
  __shared__ float redmax[4][16];
  __shared__ float redsum[4][16];
  __shared__ float ctxp[4][16][64];

  int bh = blockIdx.y;
  int b = bh / 12, h = bh - b * 12;
  int q0 = blockIdx.x * 16;
  const short* Qp = Qb + ((size_t)bh * 1024 + q0) * 64;
  const short* Kp = Kb + (size_t)bh * 1024 * 64;
  const short* Vp = Vtb + (size_t)bh * 64 * 1024;
  const int* mb = amask + b * 1024;

  int t = threadIdx.x, w = t >> 6, lane = t & 63;
  int lr = lane & 15, lk = (lane >> 4) * 8;

  // Q A-frags (row = lr, k = kk*32 + lk + 0..7)
  short8 aq0 = *(const short8*)&Qp[lr * 64 + lk];
  short8 aq1 = *(const short8*)&Qp[lr * 64 + 32 + lk];

  float4v acc[16] = {};
#pragma unroll
  for (int nt = 0; nt < 16; nt++) {
    const short* kp = Kp + (size_t)(w * 256 + nt * 16 + lr) * 64;
    short8 b0 = *(const short8*)&kp[lk];
    short8 b1 = *(const short8*)&kp[32 + lk];
    acc[nt] = mfma16((const short*)&aq0, (const short*)&b0, acc[nt]);
    acc[nt] = mfma16((const short*)&aq1, (const short*)&b1, acc[nt]);
  }

  unsigned mbits = 0;
#pragma unroll
  for (int nt = 0; nt < 16; nt++)
    mbits |= (mb[w * 256 + nt * 16 + lr] != 0 ? 1u : 0u) << nt;

  // scale + mask + row max (rows r = (lane>>4)*4 + j)
  float mx[4] = {-1e30f, -1e30f, -1e30f, -1e30f};
#pragma unroll
  for (int nt = 0; nt < 16; nt++)
#pragma unroll
    for (int j = 0; j < 4; j++) {
      float s = acc[nt][j] * 0.125f;
      if (!((mbits >> nt) & 1)) s = -1e30f;
      acc[nt][j] = s;
      mx[j] = fmaxf(mx[j], s);
    }
#pragma unroll
  for (int j = 0; j < 4; j++) {
#pragma unroll
    for (int off = 1; off < 16; off <<= 1) mx[j] = fmaxf(mx[j], __shfl_xor(mx[j], off));
  }
  if (lr == 0) {
#pragma unroll
    for (int j = 0; j < 4; j++) redmax[w][(lane >> 4) * 4 + j] = mx[j];
  }
  __syncthreads();
  float gmx[4];
#pragma unroll
  for (int j = 0; j < 4; j++) {
    int r = (lane >> 4) * 4 + j;
    gmx[j] = fmaxf(fmaxf(redmax[0][r], redmax[1][r]), fmaxf(redmax[2][r], redmax[3][r]));
  }

  float sm[4] = {0.f, 0.f, 0.f, 0.f};
#pragma unroll
  for (int nt = 0; nt < 16; nt++)
#pragma unroll
    for (int j = 0; j < 4; j++) {
      float p = ((mbits >> nt) & 1) ? __expf(acc[nt][j] - gmx[j]) : 0.f;
      acc[nt][j] = p;
      sm[j] += p;
    }
#pragma unroll
  for (int j = 0; j < 4; j++) {
#pragma unroll
    for (int off = 1; off < 16; off <<= 1) sm[j] += __shfl_xor(sm[j], off);
  }
  if (lr == 0) {
#pragma unroll
    for (int j = 0; j < 4; j++) redsum[w][(lane >> 4) * 4 + j] = sm[j];
  }
  __syncthreads();
  float inv[4];
#pragma unroll
  for (int j = 0; j < 4; j++) {
    int r = (lane >> 4) * 4 + j;
    float s = redsum[0][r] + redsum[1][r] + redsum[2][r] + redsum[3][r];
    inv[j] = (s > 0.f) ? 1.f / s : 0.f;
  }

  // write probs (fp32) + P (bf16 LDS)
  size_t pbase = ((size_t)bh * 1024 + q0) * 1024;
#pragma unroll
  for (int nt = 0; nt < 16; nt++) {
    int col = w * 256 + nt * 16 + lr;
#pragma unroll
    for (int j = 0; j < 4; j++) {
      int row = (lane >> 4) * 4 + j;
      float pv = acc[nt][j] * inv[j];
      probs[pbase + (size_t)row * 1024 + col] = pv;
      P[row][col] = f2bf(pv);
    }
  }
  __syncthreads();

  // PV: wave w handles k in [w*256, w*256+256)
  float4v c[4] = {};
#pragma unroll
  for (int ks = 0; ks < 8; ks++) {
    int kbase = w * 256 + ks * 32;
    short8 ap = *(const short8*)&P[lr][kbase + lk];
#pragma unroll
    for (int n2 = 0; n2 < 4; n2++) {
      short8 bvv = *(const short8*)&Vp[(size_t)(n2 * 16 + lr) * 1024 + kbase + lk];
      c[n2] = mfma16((const short*)&ap, (const short*)&bvv, c[n2]);
    }
  }
#pragma unroll
  for (int n2 = 0; n2 < 4; n2++)
#pragma unroll
    for (int j = 0; j < 4; j++)
      ctxp[w][(lane >> 4) * 4 + j][n2 * 16 + lr] = c[n2][j];
  __syncthreads();

  // reduce 4 waves' partials, store ctx bf16 [B,S,D]
#pragma unroll
  for (int u = 0; u < 4; u++) {
    int o = t * 4 + u;
    int row = o >> 6, dh = o & 63;
    float s = ctxp[0][row][dh] + ctxp[1][row][dh] + ctxp[2][row][dh] + ctxp[3][row][dh];
    ctxb[((size_t)(b * 1024 + q0 + row)) * 768 + h * 64 + dh] = f2bf(s);
  }
}

// ---------------- O projection (NT) + bias + residual -> h fp32 ----------------
__global__ __launch_bounds__(256) void gemm_o(const short* __restrict__ A,
                                              const short* __restrict__ Bw,
                                              const float* __restrict__ bo,
                                              const float* __restrict__ hidden,
                                              float* __restrict__ hout) {
  __shared__ short As[128][AST];
  __shared__ short Bs[128][AST];
  int m0 = blockIdx.x * 128, n0 = blockIdx.y * 128;
  int t = threadIdx.x;
  int w = t >> 6, lane = t & 63;
  int wm = (w >> 1) * 64, wn = (w & 1) * 64;
  int lr = lane & 15, lk = (lane >> 4) * 8;
  int sr = t >> 2, sc = (t & 3) * 8;

  float4v acc[4][4] = {};

  for (int k0 = 0; k0 < 768; k0 += 32) {
    *(short8*)&As[sr][sc]      = *(const short8*)&A[(size_t)(m0 + sr) * 768 + k0 + sc];
    *(short8*)&As[sr + 64][sc] = *(const short8*)&A[(size_t)(m0 + sr + 64) * 768 + k0 + sc];
    *(short8*)&Bs[sr][sc]      = *(const short8*)&Bw[(size_t)(n0 + sr) * 768 + k0 + sc];
    *(short8*)&Bs[sr + 64][sc] = *(const short8*)&Bw[(size_t)(n0 + sr + 64) * 768 + k0 + sc];
    __syncthreads();
    short8 a[4], b[4];
#pragma unroll
    for (int i = 0; i < 4; i++) a[i] = *(const short8*)&As[wm + i * 16 + lr][lk];
#pragma unroll
    for (int j = 0; j < 4; j++) b[j] = *(const short8*)&Bs[wn + j * 16 + lr][lk];
#pragma unroll
    for (int i = 0; i < 4; i++)
#pragma unroll
      for (int j = 0; j < 4; j++)
        acc[i][j] = mfma16((const short*)&a[i], (const short*)&b[j], acc[i][j]);
    __syncthreads();
  }

#pragma unroll
  for (int j = 0; j < 4; j++) {
    int gn = n0 + wn + j * 16 + lr;
    float bb = bo[gn];
#pragma unroll
    for (int i = 0; i < 4; i++) {
      int gm0 = m0 + wm + i * 16 + ((lane >> 4) << 2);
#pragma unroll
      for (int jj = 0; jj < 4; jj++) {
        int r = gm0 + jj;
        size_t idx = (size_t)r * 768 + gn;
        hout[idx] = acc[i][j][jj] + bb + hidden[idx];
      }
    }
  }
}

// ---------------- LayerNorm over D=768 ----------------
__global__ __launch_bounds__(256) void lnorm(const float* __restrict__ h,
                                             const float* __restrict__ g,
                                             const float* __restrict__ be,
                                             float* __restrict__ out) {
  int row = blockIdx.x;
  const float* x = h + (size_t)row * 768;
  int t = threadIdx.x;
  float v0 = x[t], v1 = x[t + 256], v2 = x[t + 512];
  float s = v0 + v1 + v2;
#pragma unroll
  for (int off = 1; off < 64; off <<= 1) s += __shfl_xor(s, off);
  __shared__ float r1[4], r2[4];
  if ((t & 63) == 0) r1[t >> 6] = s;
  __syncthreads();
  float mean = (r1[0] + r1[1] + r1[2] + r1[3]) * (1.f / 768.f);
  float d0 = v0 - mean, d1 = v1 - mean, d2 = v2 - mean;
  float q = d0 * d0 + d1 * d1 + d2 * d2;
#pragma unroll
  for (int off = 1; off < 64; off <<= 1) q += __shfl_xor(q, off);
  if ((t & 63) == 0) r2[t >> 6] = q;
  __syncthreads();
  float var = (r2[0] + r2[1] + r2[2] + r2[3]) * (1.f / 768.f);
  float rr = rsqrtf(var + 1e-12f);
  size_t o = (size_t)row * 768;
  out[o + t]       = d0 * rr * g[t] + be[t];
  out[o + t + 256] = d1 * rr * g[t + 256] + be[t + 256];
  out[o + t + 512] = d2 * rr * g[t + 512] + be[t + 512];
}

extern "C" void kernel_launch(void* const* d_in, const int* in_sizes, int n_in,
                              void* d_out, int out_size, void* d_ws, size_t ws_size,
                              hipStream_t stream) {
  const float* hs    = (const float*)d_in[0];
  const int*   amask = (const int*)d_in[1];
  const float* Wq    = (const float*)d_in[2];
  const float* bq    = (const float*)d_in[3];
  const float* Wk    = (const float*)d_in[4];
  const float* bk    = (const float*)d_in[5];
  const float* Wv    = (const float*)d_in[6];
  const float* bv    = (const float*)d_in[7];
  const float* Wo    = (const float*)d_in[8];
  const float* bo    = (const float*)d_in[9];
  const float* lng   = (const float*)d_in[10];
  const float* lnb   = (const float*)d_in[11];

  char* wsp = (char*)d_ws;
  const size_t NTOK = (size_t)B_ * S_;  // 8192
  short* hsb  = (short*)wsp; wsp += NTOK * D_ * 2;
  short* wqkv = (short*)wsp; wsp += (size_t)3 * D_ * D_ * 2;
  short* wob  = (short*)wsp; wsp += (size_t)D_ * D_ * 2;
  short* Qb   = (short*)wsp; wsp += NTOK * D_ * 2;
  short* Kb   = (short*)wsp; wsp += NTOK * D_ * 2;
  short* Vtb  = (short*)wsp; wsp += NTOK * D_ * 2;
  short* ctxb = (short*)wsp; wsp += NTOK * D_ * 2;
  float* hbuf = (float*)wsp; wsp += NTOK * D_ * 4;

  float* out   = (float*)d_out;
  float* probs = out + NTOK * D_;

  int n4hs = (int)(NTOK * D_ / 4);
  cvt_bf16<<<dim3((n4hs + 255) / 256), dim3(256), 0, stream>>>(hs, hsb, n4hs);
  int n4w = D_ * D_ / 4;
  dim3 wg((n4w + 255) / 256);
  cvt_bf16<<<wg, dim3(256), 0, stream>>>(Wq, wqkv, n4w);
  cvt_bf16<<<wg, dim3(256), 0, stream>>>(Wk, wqkv + (size_t)D_ * D_, n4w);
  cvt_bf16<<<wg, dim3(256), 0, stream>>>(Wv, wqkv + (size_t)2 * D_ * D_, n4w);
  cvt_bf16<<<wg, dim3(256), 0, stream>>>(Wo, wob, n4w);

  gemm_qkv<<<dim3(64, 18), dim3(256), 0, stream>>>(hsb, wqkv, bq, bk, bv, Qb, Kb, Vtb);
  attn_fused<<<dim3(S_ / 16, B_ * H_), dim3(256), 0, stream>>>(Qb, Kb, Vtb, amask, probs, ctxb);
  gemm_o<<<dim3(64, 6), dim3(256), 0, stream>>>(ctxb, wob, bo, hs, hbuf);
  lnorm<<<dim3(8192), dim3(256), 0, stream>>>(hbuf, lng, lnb, out);
}

// Round 3
// 732.737 us; speedup vs baseline: 1.0357x; 1.0357x over previous
//
#include <hip/hip_runtime.h>

#define B_ 8
#define S_ 1024
#define D_ 768
#define H_ 12
#define DH_ 64

typedef __attribute__((ext_vector_type(8))) short short8;
typedef __attribute__((ext_vector_type(4))) short short4v;
typedef __attribute__((ext_vector_type(4))) float float4v;
typedef __attribute__((ext_vector_type(8))) __bf16 bf16x8;

static __device__ __forceinline__ short f2bf(float f) {
  union { float f; unsigned u; } v; v.f = f;
  unsigned r = v.u + 0x7fffu + ((v.u >> 16) & 1u);
  return (short)(r >> 16);
}
static __device__ __forceinline__ float bf2f(short s) {
  union { unsigned u; float f; } v; v.u = ((unsigned)(unsigned short)s) << 16;
  return v.f;
}

static __device__ __forceinline__ float4v mfma16(const short* ap, const short* bp, float4v c) {
  bf16x8 a = *(const bf16x8*)ap;
  bf16x8 b = *(const bf16x8*)bp;
  return __builtin_amdgcn_mfma_f32_16x16x32_bf16(a, b, c, 0, 0, 0);
}

typedef const __attribute__((address_space(1))) unsigned gu32;
typedef __attribute__((address_space(3))) unsigned lu32;
// async global->LDS, 16B per lane; LDS dest = wave-uniform base + lane*16
static __device__ __forceinline__ void gload16(const void* g, void* l) {
  __builtin_amdgcn_global_load_lds((gu32*)g, (lu32*)l, 16, 0, 0);
}

// ---------------- fp32 -> bf16 conversion ----------------
__global__ __launch_bounds__(256) void cvt_bf16(const float* __restrict__ src,
                                                short* __restrict__ dst, int n4) {
  int i = blockIdx.x * 256 + threadIdx.x;
  if (i < n4) {
    float4v v = ((const float4v*)src)[i];
    short4v o;
    o.x = f2bf(v.x); o.y = f2bf(v.y); o.z = f2bf(v.z); o.w = f2bf(v.w);
    ((short4v*)dst)[i] = o;
  }
}

// ---------------- QKV projection GEMM (NT): C[8192][2304] = hs_bf16 @ Wqkv^T ----------------
// 128x128 tile, BK=32, 4 waves (2x2); global_load_lds staging (linear LDS, m97 structure);
// epilogue via LDS C-tile (overlaid on As/Bs) with vectorized coalesced stores.
__global__ __launch_bounds__(256) void gemm_qkv(const short* __restrict__ A,
                                                const short* __restrict__ Bw,
                                                const float* __restrict__ bq,
                                                const float* __restrict__ bk,
                                                const float* __restrict__ bv,
                                                short* __restrict__ Qb,
                                                short* __restrict__ Kb,
                                                short* __restrict__ Vtb) {
  __shared__ char smem[34816];                       // Cs[128][136] overlay; As+Bs = 16KB
  short (*As)[32] = (short(*)[32])smem;
  short (*Bs)[32] = (short(*)[32])(smem + 8192);
  short (*Cs)[136] = (short(*)[136])smem;

  int m0 = blockIdx.x * 128, n0 = blockIdx.y * 128;
  int t = threadIdx.x, w = t >> 6, lane = t & 63;
  int wm = (w >> 1) * 64, wn = (w & 1) * 64;
  int lr = lane & 15, lk = (lane >> 4) * 8;

  // staging: wave w stages rows [w*32, w*32+32) of each tile; lane -> (row=lane/4, col=(lane%4)*8)
  const short* gA = A + (size_t)(m0 + w * 32 + (lane >> 2)) * 768 + (lane & 3) * 8;
  const short* gB = Bw + (size_t)(n0 + w * 32 + (lane >> 2)) * 768 + (lane & 3) * 8;

  float4v acc[4][4] = {};

  for (int k0 = 0; k0 < 768; k0 += 32) {
    gload16(gA, &As[w * 32][0]);
    gload16(gA + 16 * 768, &As[w * 32 + 16][0]);
    gload16(gB, &Bs[w * 32][0]);
    gload16(gB + 16 * 768, &Bs[w * 32 + 16][0]);
    gA += 32; gB += 32;
    __syncthreads();
    short8 a[4], b[4];
#pragma unroll
    for (int i = 0; i < 4; i++) a[i] = *(const short8*)&As[wm + i * 16 + lr][lk];
#pragma unroll
    for (int j = 0; j < 4; j++) b[j] = *(const short8*)&Bs[wn + j * 16 + lr][lk];
#pragma unroll
    for (int i = 0; i < 4; i++)
#pragma unroll
      for (int j = 0; j < 4; j++)
        acc[i][j] = mfma16((const short*)&a[i], (const short*)&b[j], acc[i][j]);
    __syncthreads();
  }

  int proj = blockIdx.y / 6;                 // 0=Q 1=K 2=V
  int nloc0 = n0 - proj * 768;
  int hhb = nloc0 >> 6;                      // first of 2 heads in this col-tile
  int b = m0 >> 10, s0v = m0 & 1023;

  if (proj < 2) {
    short* dst = (proj == 0) ? Qb : Kb;
    const float* bias = (proj == 0) ? bq : bk;
    // Cs[s_local][col_local]
#pragma unroll
    for (int j = 0; j < 4; j++) {
      float bb = bias[nloc0 + wn + j * 16 + lr];
#pragma unroll
      for (int i = 0; i < 4; i++)
#pragma unroll
        for (int jj = 0; jj < 4; jj++)
          Cs[wm + i * 16 + (lane >> 4) * 4 + jj][wn + j * 16 + lr] = f2bf(acc[i][j][jj] + bb);
    }
    __syncthreads();
    // per head: 128 s-rows x 64 dh = contiguous 16KB region
#pragma unroll
    for (int hh2 = 0; hh2 < 2; hh2++) {
      short* base = dst + ((size_t)(b * 12 + hhb + hh2) * 1024 + s0v) * 64;
#pragma unroll
      for (int u = 0; u < 4; u++) {
        int c = t + u * 256;
        int sl = c >> 3, dh0 = (c & 7) * 8;
        *(short8*)&base[(size_t)c * 8] = *(const short8*)&Cs[sl][hh2 * 64 + dh0];
      }
    }
  } else {
    // V: transposed LDS tile Cs[col_local][s_local], ds_write_b64 packs 4 s
#pragma unroll
    for (int j = 0; j < 4; j++) {
      float bb = bv[nloc0 + wn + j * 16 + lr];
#pragma unroll
      for (int i = 0; i < 4; i++) {
        short4v p;
        p.x = f2bf(acc[i][j][0] + bb);
        p.y = f2bf(acc[i][j][1] + bb);
        p.z = f2bf(acc[i][j][2] + bb);
        p.w = f2bf(acc[i][j][3] + bb);
        *(short4v*)&Cs[wn + j * 16 + lr][wm + i * 16 + (lane >> 4) * 4] = p;
      }
    }
    __syncthreads();
    // V^T rows: 128 dh-rows x 128 s (256B contiguous per row; 16 lanes/row)
#pragma unroll
    for (int u = 0; u < 8; u++) {
      int row = (t >> 4) + u * 16;
      int hh2 = row >> 6, dh = row & 63;
      *(short8*)&Vtb[((size_t)(b * 12 + hhb + hh2) * 64 + dh) * 1024 + s0v + (t & 15) * 8]
          = *(const short8*)&Cs[row][(t & 15) * 8];
    }
  }
}

// ---------------- fused attention: per (b,h,q-tile of 16) ----------------
__global__ __launch_bounds__(256) void attn_fused(const short* __restrict__ Qb,
                                                  const short* __restrict__ Kb,
                                                  const short* __restrict__ Vtb,
                                                  const int* __restrict__ amask,
                                                  float* __restrict__ probs,
                                                  short* __restrict__ ctxb) {
  __shared__ short P[16][1032];
  __shared__ float redmax[4][16];
  __shared__ float redsum[4][16];
  __shared__ float ctxp[4][16][64];

  int bh = blockIdx.y;
  int b = bh / 12, h = bh - b * 12;
  int q0 = blockIdx.x * 16;
  const short* Qp = Qb + ((size_t)bh * 1024 + q0) * 64;
  const short* Kp = Kb + (size_t)bh * 1024 * 64;
  const short* Vp = Vtb + (size_t)bh * 64 * 1024;
  const int* mb = amask + b * 1024;

  int t = threadIdx.x, w = t >> 6, lane = t & 63;
  int lr = lane & 15, lk = (lane >> 4) * 8;

  short8 aq0 = *(const short8*)&Qp[lr * 64 + lk];
  short8 aq1 = *(const short8*)&Qp[lr * 64 + 32 + lk];

  float4v acc[16] = {};
#pragma unroll
  for (int nt = 0; nt < 16; nt++) {
    const short* kp = Kp + (size_t)(w * 256 + nt * 16 + lr) * 64;
    short8 b0 = *(const short8*)&kp[lk];
    short8 b1 = *(const short8*)&kp[32 + lk];
    acc[nt] = mfma16((const short*)&aq0, (const short*)&b0, acc[nt]);
    acc[nt] = mfma16((const short*)&aq1, (const short*)&b1, acc[nt]);
  }

  unsigned mbits = 0;
#pragma unroll
  for (int nt = 0; nt < 16; nt++)
    mbits |= (mb[w * 256 + nt * 16 + lr] != 0 ? 1u : 0u) << nt;

  float mx[4] = {-1e30f, -1e30f, -1e30f, -1e30f};
#pragma unroll
  for (int nt = 0; nt < 16; nt++)
#pragma unroll
    for (int j = 0; j < 4; j++) {
      float s = acc[nt][j] * 0.125f;
      if (!((mbits >> nt) & 1)) s = -1e30f;
      acc[nt][j] = s;
      mx[j] = fmaxf(mx[j], s);
    }
#pragma unroll
  for (int j = 0; j < 4; j++) {
#pragma unroll
    for (int off = 1; off < 16; off <<= 1) mx[j] = fmaxf(mx[j], __shfl_xor(mx[j], off));
  }
  if (lr == 0) {
#pragma unroll
    for (int j = 0; j < 4; j++) redmax[w][(lane >> 4) * 4 + j] = mx[j];
  }
  __syncthreads();
  float gmx[4];
#pragma unroll
  for (int j = 0; j < 4; j++) {
    int r = (lane >> 4) * 4 + j;
    gmx[j] = fmaxf(fmaxf(redmax[0][r], redmax[1][r]), fmaxf(redmax[2][r], redmax[3][r]));
  }

  float sm[4] = {0.f, 0.f, 0.f, 0.f};
#pragma unroll
  for (int nt = 0; nt < 16; nt++)
#pragma unroll
    for (int j = 0; j < 4; j++) {
      float p = ((mbits >> nt) & 1) ? __expf(acc[nt][j] - gmx[j]) : 0.f;
      acc[nt][j] = p;
      sm[j] += p;
    }
#pragma unroll
  for (int j = 0; j < 4; j++) {
#pragma unroll
    for (int off = 1; off < 16; off <<= 1) sm[j] += __shfl_xor(sm[j], off);
  }
  if (lr == 0) {
#pragma unroll
    for (int j = 0; j < 4; j++) redsum[w][(lane >> 4) * 4 + j] = sm[j];
  }
  __syncthreads();
  float inv[4];
#pragma unroll
  for (int j = 0; j < 4; j++) {
    int r = (lane >> 4) * 4 + j;
    float s = redsum[0][r] + redsum[1][r] + redsum[2][r] + redsum[3][r];
    inv[j] = (s > 0.f) ? 1.f / s : 0.f;
  }

  // normalize -> P (bf16, LDS only)
#pragma unroll
  for (int nt = 0; nt < 16; nt++) {
    int col = w * 256 + nt * 16 + lr;
#pragma unroll
    for (int j = 0; j < 4; j++) {
      int row = (lane >> 4) * 4 + j;
      P[row][col] = f2bf(acc[nt][j] * inv[j]);
    }
  }
  __syncthreads();

  // vectorized probs write from P: 16 lanes x float4 = 256B contiguous per row-group
  size_t pbase = ((size_t)bh * 1024 + q0) * 1024;
  {
    int prow = t >> 4;
    int cb = (t & 15) * 4;
    float* orow = probs + pbase + (size_t)prow * 1024;
#pragma unroll
    for (int u = 0; u < 16; u++) {
      int col = cb + u * 64;
      short4v pv = *(const short4v*)&P[prow][col];
      float4v f;
      f.x = bf2f(pv.x); f.y = bf2f(pv.y); f.z = bf2f(pv.z); f.w = bf2f(pv.w);
      *(float4v*)&orow[col] = f;
    }
  }

  // PV: wave w handles k in [w*256, w*256+256)
  float4v c[4] = {};
#pragma unroll
  for (int ks = 0; ks < 8; ks++) {
    int kbase = w * 256 + ks * 32;
    short8 ap = *(const short8*)&P[lr][kbase + lk];
#pragma unroll
    for (int n2 = 0; n2 < 4; n2++) {
      short8 bvv = *(const short8*)&Vp[(size_t)(n2 * 16 + lr) * 1024 + kbase + lk];
      c[n2] = mfma16((const short*)&ap, (const short*)&bvv, c[n2]);
    }
  }
#pragma unroll
  for (int n2 = 0; n2 < 4; n2++)
#pragma unroll
    for (int j = 0; j < 4; j++)
      ctxp[w][(lane >> 4) * 4 + j][n2 * 16 + lr] = c[n2][j];
  __syncthreads();

  {
    int row = t >> 4, dh0 = (t & 15) * 4;
    short4v o4;
    float s0 = ctxp[0][row][dh0 + 0] + ctxp[1][row][dh0 + 0] + ctxp[2][row][dh0 + 0] + ctxp[3][row][dh0 + 0];
    float s1 = ctxp[0][row][dh0 + 1] + ctxp[1][row][dh0 + 1] + ctxp[2][row][dh0 + 1] + ctxp[3][row][dh0 + 1];
    float s2 = ctxp[0][row][dh0 + 2] + ctxp[1][row][dh0 + 2] + ctxp[2][row][dh0 + 2] + ctxp[3][row][dh0 + 2];
    float s3 = ctxp[0][row][dh0 + 3] + ctxp[1][row][dh0 + 3] + ctxp[2][row][dh0 + 3] + ctxp[3][row][dh0 + 3];
    o4.x = f2bf(s0); o4.y = f2bf(s1); o4.z = f2bf(s2); o4.w = f2bf(s3);
    *(short4v*)&ctxb[((size_t)(b * 1024 + q0 + row)) * 768 + h * 64 + dh0] = o4;
  }
}

// ---------------- O projection (NT) + bias + residual -> h fp32 ----------------
__global__ __launch_bounds__(256) void gemm_o(const short* __restrict__ A,
                                              const short* __restrict__ Bw,
                                              const float* __restrict__ bo,
                                              const float* __restrict__ hidden,
                                              float* __restrict__ hout) {
  __shared__ short As[128][32];
  __shared__ short Bs[128][32];
  int m0 = blockIdx.x * 128, n0 = blockIdx.y * 128;
  int t = threadIdx.x, w = t >> 6, lane = t & 63;
  int wm = (w >> 1) * 64, wn = (w & 1) * 64;
  int lr = lane & 15, lk = (lane >> 4) * 8;

  const short* gA = A + (size_t)(m0 + w * 32 + (lane >> 2)) * 768 + (lane & 3) * 8;
  const short* gB = Bw + (size_t)(n0 + w * 32 + (lane >> 2)) * 768 + (lane & 3) * 8;

  float4v acc[4][4] = {};

  for (int k0 = 0; k0 < 768; k0 += 32) {
    gload16(gA, &As[w * 32][0]);
    gload16(gA + 16 * 768, &As[w * 32 + 16][0]);
    gload16(gB, &Bs[w * 32][0]);
    gload16(gB + 16 * 768, &Bs[w * 32 + 16][0]);
    gA += 32; gB += 32;
    __syncthreads();
    short8 a[4], b[4];
#pragma unroll
    for (int i = 0; i < 4; i++) a[i] = *(const short8*)&As[wm + i * 16 + lr][lk];
#pragma unroll
    for (int j = 0; j < 4; j++) b[j] = *(const short8*)&Bs[wn + j * 16 + lr][lk];
#pragma unroll
    for (int i = 0; i < 4; i++)
#pragma unroll
      for (int j = 0; j < 4; j++)
        acc[i][j] = mfma16((const short*)&a[i], (const short*)&b[j], acc[i][j]);
    __syncthreads();
  }

#pragma unroll
  for (int j = 0; j < 4; j++) {
    int gn = n0 + wn + j * 16 + lr;
    float bb = bo[gn];
#pragma unroll
    for (int i = 0; i < 4; i++) {
      int gm0 = m0 + wm + i * 16 + ((lane >> 4) << 2);
#pragma unroll
      for (int jj = 0; jj < 4; jj++) {
        int r = gm0 + jj;
        size_t idx = (size_t)r * 768 + gn;
        hout[idx] = acc[i][j][jj] + bb + hidden[idx];
      }
    }
  }
}

// ---------------- LayerNorm over D=768 ----------------
__global__ __launch_bounds__(256) void lnorm(const float* __restrict__ h,
                                             const float* __restrict__ g,
                                             const float* __restrict__ be,
                                             float* __restrict__ out) {
  int row = blockIdx.x;
  const float* x = h + (size_t)row * 768;
  int t = threadIdx.x;
  float v0 = x[t], v1 = x[t + 256], v2 = x[t + 512];
  float s = v0 + v1 + v2;
#pragma unroll
  for (int off = 1; off < 64; off <<= 1) s += __shfl_xor(s, off);
  __shared__ float r1[4], r2[4];
  if ((t & 63) == 0) r1[t >> 6] = s;
  __syncthreads();
  float mean = (r1[0] + r1[1] + r1[2] + r1[3]) * (1.f / 768.f);
  float d0 = v0 - mean, d1 = v1 - mean, d2 = v2 - mean;
  float q = d0 * d0 + d1 * d1 + d2 * d2;
#pragma unroll
  for (int off = 1; off < 64; off <<= 1) q += __shfl_xor(q, off);
  if ((t & 63) == 0) r2[t >> 6] = q;
  __syncthreads();
  float var = (r2[0] + r2[1] + r2[2] + r2[3]) * (1.f / 768.f);
  float rr = rsqrtf(var + 1e-12f);
  size_t o = (size_t)row * 768;
  out[o + t]       = d0 * rr * g[t] + be[t];
  out[o + t + 256] = d1 * rr * g[t + 256] + be[t + 256];
  out[o + t + 512] = d2 * rr * g[t + 512] + be[t + 512];
}

extern "C" void kernel_launch(void* const* d_in, const int* in_sizes, int n_in,
                              void* d_out, int out_size, void* d_ws, size_t ws_size,
                              hipStream_t stream) {
  const float* hs    = (const float*)d_in[0];
  const int*   amask = (const int*)d_in[1];
  const float* Wq    = (const float*)d_in[2];
  const float* bq    = (const float*)d_in[3];
  const float* Wk    = (const float*)d_in[4];
  const float* bk    = (const float*)d_in[5];
  const float* Wv    = (const float*)d_in[6];
  const float* bv    = (const float*)d_in[7];
  const float* Wo    = (const float*)d_in[8];
  const float* bo    = (const float*)d_in[9];
  const float* lng   = (const float*)d_in[10];
  const float* lnb   = (const float*)d_in[11];

  char* wsp = (char*)d_ws;
  const size_t NTOK = (size_t)B_ * S_;  // 8192
  short* hsb  = (short*)wsp; wsp += NTOK * D_ * 2;
  short* wqkv = (short*)wsp; wsp += (size_t)3 * D_ * D_ * 2;
  short* wob  = (short*)wsp; wsp += (size_t)D_ * D_ * 2;
  short* Qb   = (short*)wsp; wsp += NTOK * D_ * 2;
  short* Kb   = (short*)wsp; wsp += NTOK * D_ * 2;
  short* Vtb  = (short*)wsp; wsp += NTOK * D_ * 2;
  short* ctxb = (short*)wsp; wsp += NTOK * D_ * 2;
  float* hbuf = (float*)wsp; wsp += NTOK * D_ * 4;

  float* out   = (float*)d_out;
  float* probs = out + NTOK * D_;

  int n4hs = (int)(NTOK * D_ / 4);
  cvt_bf16<<<dim3((n4hs + 255) / 256), dim3(256), 0, stream>>>(hs, hsb, n4hs);
  int n4w = D_ * D_ / 4;
  dim3 wg((n4w + 255) / 256);
  cvt_bf16<<<wg, dim3(256), 0, stream>>>(Wq, wqkv, n4w);
  cvt_bf16<<<wg, dim3(256), 0, stream>>>(Wk, wqkv + (size_t)D_ * D_, n4w);
  cvt_bf16<<<wg, dim3(256), 0, stream>>>(Wv, wqkv + (size_t)2 * D_ * D_, n4w);
  cvt_bf16<<<wg, dim3(256), 0, stream>>>(Wo, wob, n4w);

  gemm_qkv<<<dim3(64, 18), dim3(256), 0, stream>>>(hsb, wqkv, bq, bk, bv, Qb, Kb, Vtb);
  attn_fused<<<dim3(S_ / 16, B_ * H_), dim3(256), 0, stream>>>(Qb, Kb, Vtb, amask, probs, ctxb);
  gemm_o<<<dim3(64, 6), dim3(256), 0, stream>>>(ctxb, wob, bo, hs, hbuf);
  lnorm<<<dim3(8192), dim3(256), 0, stream>>>(hbuf, lng, lnb, out);
}